// Round 1
// baseline (423.257 us; speedup 1.0000x reference)
//
#include <hip/hip_runtime.h>
#include <hip/hip_bf16.h>

// Problem constants (fixed by setup_inputs)
#define BB 32
#define TT 24
#define NN 325
#define DD 64
#define KH 8          // heads
#define DH 8          // head dim
#define RSTRIDE 65    // padded LDS row stride (floats) for [T][D] tiles
#define ASTRIDE 25    // padded attn row stride (floats)

// One block per (b, n). 256 threads: j = tid&63 (feature col), tg = tid>>6 (row group of 6).
__global__ __launch_bounds__(256, 3) void ta_fused_kernel(
    const float* __restrict__ X,
    const float* __restrict__ Wq, const float* __restrict__ bq,
    const float* __restrict__ Wk, const float* __restrict__ bk,
    const float* __restrict__ Wv, const float* __restrict__ bv,
    const float* __restrict__ Wf1, const float* __restrict__ bf1,
    const float* __restrict__ Wf2, const float* __restrict__ bf2,
    float* __restrict__ Out)
{
    const int blk = blockIdx.x;
    const int b = blk / NN;
    const int n = blk - b * NN;
    const int tid = threadIdx.x;
    const int j  = tid & 63;
    const int tg = tid >> 6;   // 0..3, each owns 6 t-rows

    __shared__ float Xs[TT * RSTRIDE];    // X tile; reused as 'out' tile after attention
    __shared__ float qs[TT * RSTRIDE];    // q tile; reused as 'h' tile in FF
    __shared__ float ks_[TT * RSTRIDE];
    __shared__ float vs[TT * RSTRIDE];
    __shared__ float attn[KH * TT * ASTRIDE];

    // ---- Phase 0: load X[b, :, n, :] (24 rows x 64) ----
    #pragma unroll
    for (int i = 0; i < 6; ++i) {
        const int t = tg * 6 + i;
        Xs[t * RSTRIDE + j] = X[((size_t)(b * TT + t) * NN + n) * DD + j];
    }
    __syncthreads();

    // ---- Phase 1: q,k,v = relu(X@W + b) ----
    {
        float accq[6], acck[6], accv[6];
        const float bqj = bq[j], bkj = bk[j], bvj = bv[j];
        #pragma unroll
        for (int i = 0; i < 6; ++i) { accq[i] = bqj; acck[i] = bkj; accv[i] = bvj; }
        for (int dd = 0; dd < DD; ++dd) {
            const float wq = Wq[dd * DD + j];
            const float wk = Wk[dd * DD + j];
            const float wv = Wv[dd * DD + j];
            #pragma unroll
            for (int i = 0; i < 6; ++i) {
                const float x = Xs[(tg * 6 + i) * RSTRIDE + dd];  // wave-broadcast
                accq[i] = fmaf(x, wq, accq[i]);
                acck[i] = fmaf(x, wk, acck[i]);
                accv[i] = fmaf(x, wv, accv[i]);
            }
        }
        #pragma unroll
        for (int i = 0; i < 6; ++i) {
            const int t = tg * 6 + i;
            qs [t * RSTRIDE + j] = fmaxf(accq[i], 0.f);
            ks_[t * RSTRIDE + j] = fmaxf(acck[i], 0.f);
            vs [t * RSTRIDE + j] = fmaxf(accv[i], 0.f);
        }
    }
    __syncthreads();

    // ---- Phase 2: scores + causal(upper-tri) softmax, one thread per (head, t) ----
    if (tid < KH * TT) {
        const int t  = tid % TT;
        const int kh = tid / TT;
        float qreg[DH];
        #pragma unroll
        for (int dd = 0; dd < DH; ++dd) qreg[dd] = qs[t * RSTRIDE + kh * DH + dd];
        float row[TT];
        #pragma unroll
        for (int s = 0; s < TT; ++s) {
            float acc = 0.f;
            #pragma unroll
            for (int dd = 0; dd < DH; ++dd)
                acc = fmaf(qreg[dd], ks_[s * RSTRIDE + kh * DH + dd], acc);
            row[s] = acc * 0.35355339059327373f;   // 1/sqrt(8)
        }
        // keep s >= t (triu incl. diagonal); masked -> exactly 0 after exp underflow
        float mx = -1e30f;
        #pragma unroll
        for (int s = 0; s < TT; ++s) if (s >= t) mx = fmaxf(mx, row[s]);
        float sum = 0.f;
        #pragma unroll
        for (int s = 0; s < TT; ++s) {
            const float e = (s >= t) ? expf(row[s] - mx) : 0.f;
            row[s] = e;
            sum += e;
        }
        const float inv = 1.f / sum;
        #pragma unroll
        for (int s = 0; s < TT; ++s)
            attn[(kh * TT + t) * ASTRIDE + s] = row[s] * inv;
    }
    __syncthreads();

    // ---- Phase 3: out[t][j] = sum_s attn[k(j)][t][s] * v[s][j]  (into Xs) ----
    {
        float acco[6];
        const int kh2 = j >> 3;
        #pragma unroll
        for (int i = 0; i < 6; ++i) acco[i] = 0.f;
        for (int s = 0; s < TT; ++s) {
            const float vv = vs[s * RSTRIDE + j];
            #pragma unroll
            for (int i = 0; i < 6; ++i) {
                const int t = tg * 6 + i;
                acco[i] = fmaf(attn[(kh2 * TT + t) * ASTRIDE + s], vv, acco[i]);
            }
        }
        __syncthreads();   // ensure phase-1 readers of Xs are done (they are; cheap safety)
        #pragma unroll
        for (int i = 0; i < 6; ++i)
            Xs[(tg * 6 + i) * RSTRIDE + j] = acco[i];
    }
    __syncthreads();

    // ---- Phase 4: h = relu(out@Wf1 + bf1)  (into qs) ----
    {
        float acc1[6];
        const float b1 = bf1[j];
        #pragma unroll
        for (int i = 0; i < 6; ++i) acc1[i] = b1;
        for (int dd = 0; dd < DD; ++dd) {
            const float w = Wf1[dd * DD + j];
            #pragma unroll
            for (int i = 0; i < 6; ++i)
                acc1[i] = fmaf(Xs[(tg * 6 + i) * RSTRIDE + dd], w, acc1[i]);
        }
        #pragma unroll
        for (int i = 0; i < 6; ++i)
            qs[(tg * 6 + i) * RSTRIDE + j] = fmaxf(acc1[i], 0.f);
    }
    __syncthreads();

    // ---- Phase 5: y = h@Wf2 + bf2 -> global ----
    {
        float acc2[6];
        const float b2 = bf2[j];
        #pragma unroll
        for (int i = 0; i < 6; ++i) acc2[i] = b2;
        for (int dd = 0; dd < DD; ++dd) {
            const float w = Wf2[dd * DD + j];
            #pragma unroll
            for (int i = 0; i < 6; ++i)
                acc2[i] = fmaf(qs[(tg * 6 + i) * RSTRIDE + dd], w, acc2[i]);
        }
        #pragma unroll
        for (int i = 0; i < 6; ++i) {
            const int t = tg * 6 + i;
            Out[((size_t)(b * TT + t) * NN + n) * DD + j] = acc2[i];
        }
    }
}

extern "C" void kernel_launch(void* const* d_in, const int* in_sizes, int n_in,
                              void* d_out, int out_size, void* d_ws, size_t ws_size,
                              hipStream_t stream) {
    const float* X   = (const float*)d_in[0];
    // d_in[1] = STE (unused by the reference)
    const float* Wq  = (const float*)d_in[2];
    const float* bq  = (const float*)d_in[3];
    const float* Wk  = (const float*)d_in[4];
    const float* bk  = (const float*)d_in[5];
    const float* Wv  = (const float*)d_in[6];
    const float* bv  = (const float*)d_in[7];
    const float* Wf1 = (const float*)d_in[8];
    const float* bf1 = (const float*)d_in[9];
    const float* Wf2 = (const float*)d_in[10];
    const float* bf2 = (const float*)d_in[11];
    float* Out = (float*)d_out;

    dim3 grid(BB * NN);
    dim3 block(256);
    ta_fused_kernel<<<grid, block, 0, stream>>>(X, Wq, bq, Wk, bk, Wv, bv,
                                                Wf1, bf1, Wf2, bf2, Out);
}

// Round 2
// 277.616 us; speedup vs baseline: 1.5246x; 1.5246x over previous
//
#include <hip/hip_runtime.h>
#include <hip/hip_bf16.h>

#define BB 32
#define TT 24
#define NN 325
#define DD 64
#define RS 68   // padded LDS row stride (floats)

typedef _Float16 h4 __attribute__((ext_vector_type(4)));
typedef float    f4 __attribute__((ext_vector_type(4)));

// ---------------- prep: W (f32, [k][col]) -> Wt (f16, [col][k]) ----------------
__global__ void prep_w_kernel(const float* __restrict__ Wq, const float* __restrict__ Wk,
                              const float* __restrict__ Wv, const float* __restrict__ Wf1,
                              const float* __restrict__ Wf2, _Float16* __restrict__ Wt)
{
    __shared__ float tile[64][65];
    const float* W;
    switch (blockIdx.x) {
        case 0: W = Wq; break;
        case 1: W = Wk; break;
        case 2: W = Wv; break;
        case 3: W = Wf1; break;
        default: W = Wf2; break;
    }
    const int tid = threadIdx.x;
    const int g = tid >> 6, c = tid & 63;
    #pragma unroll
    for (int p = 0; p < 16; ++p) {
        const int row = p * 4 + g;
        tile[row][c] = W[row * 64 + c];
    }
    __syncthreads();
    _Float16* dst = Wt + blockIdx.x * 4096;
    #pragma unroll
    for (int p = 0; p < 16; ++p) {
        const int col = p * 4 + g;
        dst[col * 64 + c] = (_Float16)tile[c][col];  // Wt[col][k], k = c (coalesced 2B writes)
    }
}

// ---------------- main fused kernel: one block per (b, n) ----------------
__global__ __launch_bounds__(256, 4) void ta_mfma_kernel(
    const float* __restrict__ X, const _Float16* __restrict__ Wt,
    const float* __restrict__ bq, const float* __restrict__ bk,
    const float* __restrict__ bv, const float* __restrict__ bf1,
    const float* __restrict__ bf2, float* __restrict__ Out)
{
    const int blk = blockIdx.x;
    const int b = blk / NN, n = blk - b * NN;
    const int tid  = threadIdx.x;
    const int lane = tid & 63;
    const int w    = tid >> 6;     // wave id: owns output cols [16w, 16w+16)
    const int lr   = lane & 15;    // row (A/D) or col (B/D) within 16-tile
    const int lg   = lane >> 4;    // k-quad / row-quad group

    __shared__ float qs[TT * RS];  // q, then out (in-place)
    __shared__ float ks[TT * RS];  // k, unused after attention
    __shared__ float vs[TT * RS];  // v, then h (FF1 output)

    const size_t xbase = (((size_t)b * TT) * NN + n) * DD;

    // ---- A fragments of X: 2 M-tiles x 4 K-tiles, classic 16x16x16 layout ----
    h4 a[2][4];
    #pragma unroll
    for (int mt = 0; mt < 2; ++mt) {
        const int row = mt * 16 + lr;
        const bool ok = row < TT;
        const float* xp = X + xbase + (size_t)row * (NN * DD);
        #pragma unroll
        for (int kt = 0; kt < 4; ++kt) {
            f4 x = {0.f, 0.f, 0.f, 0.f};
            if (ok) x = *(const f4*)(xp + kt * 16 + lg * 4);
            h4 h;
            h[0] = (_Float16)x[0]; h[1] = (_Float16)x[1];
            h[2] = (_Float16)x[2]; h[3] = (_Float16)x[3];
            a[mt][kt] = h;
        }
    }

    const int col = 16 * w + lr;

    // ---- QKV: q,k,v = relu(X@W + b) via MFMA ----
    {
        const _Float16* wbase = Wt + col * 64 + lg * 4;
        #pragma unroll
        for (int m = 0; m < 3; ++m) {
            const float* bias = (m == 0) ? bq : (m == 1) ? bk : bv;
            float* dst        = (m == 0) ? qs : (m == 1) ? ks : vs;
            h4 bf[4];
            #pragma unroll
            for (int kt = 0; kt < 4; ++kt)
                bf[kt] = *(const h4*)(wbase + m * 4096 + kt * 16);
            const float bb = bias[col];
            f4 acc0 = {bb, bb, bb, bb};
            f4 acc1 = acc0;
            #pragma unroll
            for (int kt = 0; kt < 4; ++kt) {
                acc0 = __builtin_amdgcn_mfma_f32_16x16x16f16(a[0][kt], bf[kt], acc0, 0, 0, 0);
                acc1 = __builtin_amdgcn_mfma_f32_16x16x16f16(a[1][kt], bf[kt], acc1, 0, 0, 0);
            }
            #pragma unroll
            for (int r = 0; r < 4; ++r) {
                const int row0 = 4 * lg + r;
                dst[row0 * RS + col] = fmaxf(acc0[r], 0.f);
                const int row1 = 16 + 4 * lg + r;
                if (row1 < TT) dst[row1 * RS + col] = fmaxf(acc1[r], 0.f);
            }
        }
    }
    __syncthreads();

    // ---- fused scores + causal softmax + PV: thread = (head kh, row t) ----
    // t = tid>>3 groups each wave to 8 consecutive t -> wave-uniform skip of s < t8.
    if (tid < 192) {
        const int kh = tid & 7;
        const int t  = tid >> 3;        // 0..23
        const int t8 = w * 8;           // wave-uniform lower bound of t in this wave
        const int coff = kh * 8;

        const f4 qa = *(const f4*)&qs[t * RS + coff];
        const f4 qb = *(const f4*)&qs[t * RS + coff + 4];

        float sc[TT];
        float mx = -3.0e38f;
        #pragma unroll
        for (int s = 0; s < TT; ++s) {
            if (s >= t8) {
                const f4 ka = *(const f4*)&ks[s * RS + coff];
                const f4 kb = *(const f4*)&ks[s * RS + coff + 4];
                float d = qa[0]*ka[0] + qa[1]*ka[1] + qa[2]*ka[2] + qa[3]*ka[3]
                        + qb[0]*kb[0] + qb[1]*kb[1] + qb[2]*kb[2] + qb[3]*kb[3];
                d *= 0.35355339059327373f;               // 1/sqrt(8)
                d = (s >= t) ? d : -3.0e38f;             // keep upper triangle
                sc[s] = d;
                mx = fmaxf(mx, d);
            }
        }
        float sum = 0.f;
        #pragma unroll
        for (int s = 0; s < TT; ++s) {
            if (s >= t8) {
                const float e = __expf(sc[s] - mx);      // masked -> exp(-huge) = 0
                sc[s] = e;
                sum += e;
            }
        }
        const float inv = 1.f / sum;
        f4 oa = {0.f, 0.f, 0.f, 0.f};
        f4 ob = {0.f, 0.f, 0.f, 0.f};
        #pragma unroll
        for (int s = 0; s < TT; ++s) {
            if (s >= t8) {
                const f4 va = *(const f4*)&vs[s * RS + coff];
                const f4 vb = *(const f4*)&vs[s * RS + coff + 4];
                const float p = sc[s];
                oa[0] += p * va[0]; oa[1] += p * va[1]; oa[2] += p * va[2]; oa[3] += p * va[3];
                ob[0] += p * vb[0]; ob[1] += p * vb[1]; ob[2] += p * vb[2]; ob[3] += p * vb[3];
            }
        }
        oa[0] *= inv; oa[1] *= inv; oa[2] *= inv; oa[3] *= inv;
        ob[0] *= inv; ob[1] *= inv; ob[2] *= inv; ob[3] *= inv;
        // in-place: each thread writes exactly the q-cells it read
        *(f4*)&qs[t * RS + coff]     = oa;
        *(f4*)&qs[t * RS + coff + 4] = ob;
    }
    __syncthreads();

    // ---- FF1: h = relu(out@Wf1 + bf1) ; out in qs -> h into vs ----
    {
        h4 fa[2][4];
        #pragma unroll
        for (int mt = 0; mt < 2; ++mt) {
            const int row = mt * 16 + lr;
            const bool ok = row < TT;
            #pragma unroll
            for (int kt = 0; kt < 4; ++kt) {
                f4 x = {0.f, 0.f, 0.f, 0.f};
                if (ok) x = *(const f4*)&qs[row * RS + kt * 16 + lg * 4];
                h4 h;
                h[0] = (_Float16)x[0]; h[1] = (_Float16)x[1];
                h[2] = (_Float16)x[2]; h[3] = (_Float16)x[3];
                fa[mt][kt] = h;
            }
        }
        const _Float16* wp = Wt + 3 * 4096 + col * 64 + lg * 4;
        h4 bf[4];
        #pragma unroll
        for (int kt = 0; kt < 4; ++kt) bf[kt] = *(const h4*)(wp + kt * 16);
        const float bb = bf1[col];
        f4 acc0 = {bb, bb, bb, bb};
        f4 acc1 = acc0;
        #pragma unroll
        for (int kt = 0; kt < 4; ++kt) {
            acc0 = __builtin_amdgcn_mfma_f32_16x16x16f16(fa[0][kt], bf[kt], acc0, 0, 0, 0);
            acc1 = __builtin_amdgcn_mfma_f32_16x16x16f16(fa[1][kt], bf[kt], acc1, 0, 0, 0);
        }
        #pragma unroll
        for (int r = 0; r < 4; ++r) {
            const int row0 = 4 * lg + r;
            vs[row0 * RS + col] = fmaxf(acc0[r], 0.f);
            const int row1 = 16 + 4 * lg + r;
            if (row1 < TT) vs[row1 * RS + col] = fmaxf(acc1[r], 0.f);
        }
    }
    __syncthreads();

    // ---- FF2: y = h@Wf2 + bf2 ; h in vs -> global ----
    {
        h4 fa[2][4];
        #pragma unroll
        for (int mt = 0; mt < 2; ++mt) {
            const int row = mt * 16 + lr;
            const bool ok = row < TT;
            #pragma unroll
            for (int kt = 0; kt < 4; ++kt) {
                f4 x = {0.f, 0.f, 0.f, 0.f};
                if (ok) x = *(const f4*)&vs[row * RS + kt * 16 + lg * 4];
                h4 h;
                h[0] = (_Float16)x[0]; h[1] = (_Float16)x[1];
                h[2] = (_Float16)x[2]; h[3] = (_Float16)x[3];
                fa[mt][kt] = h;
            }
        }
        const _Float16* wp = Wt + 4 * 4096 + col * 64 + lg * 4;
        h4 bf[4];
        #pragma unroll
        for (int kt = 0; kt < 4; ++kt) bf[kt] = *(const h4*)(wp + kt * 16);
        const float bb = bf2[col];
        f4 acc0 = {bb, bb, bb, bb};
        f4 acc1 = acc0;
        #pragma unroll
        for (int kt = 0; kt < 4; ++kt) {
            acc0 = __builtin_amdgcn_mfma_f32_16x16x16f16(fa[0][kt], bf[kt], acc0, 0, 0, 0);
            acc1 = __builtin_amdgcn_mfma_f32_16x16x16f16(fa[1][kt], bf[kt], acc1, 0, 0, 0);
        }
        #pragma unroll
        for (int r = 0; r < 4; ++r) {
            const int row0 = 4 * lg + r;
            Out[xbase + (size_t)row0 * (NN * DD) + col] = acc0[r];
            const int row1 = 16 + 4 * lg + r;
            if (row1 < TT) Out[xbase + (size_t)row1 * (NN * DD) + col] = acc1[r];
        }
    }
}

extern "C" void kernel_launch(void* const* d_in, const int* in_sizes, int n_in,
                              void* d_out, int out_size, void* d_ws, size_t ws_size,
                              hipStream_t stream) {
    const float* X   = (const float*)d_in[0];
    // d_in[1] = STE (unused by the reference)
    const float* Wq  = (const float*)d_in[2];
    const float* bq  = (const float*)d_in[3];
    const float* Wk  = (const float*)d_in[4];
    const float* bk  = (const float*)d_in[5];
    const float* Wv  = (const float*)d_in[6];
    const float* bv  = (const float*)d_in[7];
    const float* Wf1 = (const float*)d_in[8];
    const float* bf1 = (const float*)d_in[9];
    const float* Wf2 = (const float*)d_in[10];
    const float* bf2 = (const float*)d_in[11];
    float* Out = (float*)d_out;

    _Float16* Wt = (_Float16*)d_ws;   // 5 * 64*64 f16 = 40 KB

    prep_w_kernel<<<5, 256, 0, stream>>>(Wq, Wk, Wv, Wf1, Wf2, Wt);
    ta_mfma_kernel<<<BB * NN, 256, 0, stream>>>(X, Wt, bq, bk, bv, bf1, bf2, Out);
}

// Round 3
// 270.495 us; speedup vs baseline: 1.5647x; 1.0263x over previous
//
#include <hip/hip_runtime.h>
#include <hip/hip_bf16.h>

#define BB 32
#define TT 24
#define NN 325
#define DD 64
#define RSH 72   // f16 LDS row stride in halves (144 B, 16B-aligned rows)
#define RSF 68   // f32 LDS row stride in floats (272 B, 16B-aligned rows)

typedef _Float16 h4 __attribute__((ext_vector_type(4)));
typedef _Float16 h2 __attribute__((ext_vector_type(2)));
typedef float    f4 __attribute__((ext_vector_type(4)));

// ---------------- prep: W (f32, [k][col]) -> Wt (f16, [col][k]) ----------------
__global__ void prep_w_kernel(const float* __restrict__ Wq, const float* __restrict__ Wk,
                              const float* __restrict__ Wv, const float* __restrict__ Wf1,
                              const float* __restrict__ Wf2, _Float16* __restrict__ Wt)
{
    __shared__ float tile[64][65];
    const float* W;
    switch (blockIdx.x) {
        case 0: W = Wq; break;
        case 1: W = Wk; break;
        case 2: W = Wv; break;
        case 3: W = Wf1; break;
        default: W = Wf2; break;
    }
    const int tid = threadIdx.x;
    const int g = tid >> 6, c = tid & 63;
    #pragma unroll
    for (int p = 0; p < 16; ++p) {
        const int row = p * 4 + g;
        tile[row][c] = W[row * 64 + c];
    }
    __syncthreads();
    _Float16* dst = Wt + blockIdx.x * 4096;
    #pragma unroll
    for (int p = 0; p < 16; ++p) {
        const int col = p * 4 + g;
        dst[col * 64 + c] = (_Float16)tile[c][col];  // Wt[col][k]
    }
}

__device__ inline float dot8(h4 qa, h4 qb, h4 ka, h4 kb) {
#if __has_builtin(__builtin_amdgcn_fdot2)
    h2 qa0 = {qa[0], qa[1]}, qa1 = {qa[2], qa[3]};
    h2 qb0 = {qb[0], qb[1]}, qb1 = {qb[2], qb[3]};
    h2 ka0 = {ka[0], ka[1]}, ka1 = {ka[2], ka[3]};
    h2 kb0 = {kb[0], kb[1]}, kb1 = {kb[2], kb[3]};
    float d = __builtin_amdgcn_fdot2(qa0, ka0, 0.f, false);
    d = __builtin_amdgcn_fdot2(qa1, ka1, d, false);
    d = __builtin_amdgcn_fdot2(qb0, kb0, d, false);
    d = __builtin_amdgcn_fdot2(qb1, kb1, d, false);
    return d;
#else
    return (float)qa[0]*(float)ka[0] + (float)qa[1]*(float)ka[1]
         + (float)qa[2]*(float)ka[2] + (float)qa[3]*(float)ka[3]
         + (float)qb[0]*(float)kb[0] + (float)qb[1]*(float)kb[1]
         + (float)qb[2]*(float)kb[2] + (float)qb[3]*(float)kb[3];
#endif
}

// One wave per (b, n). Block = 2 independent waves. NO __syncthreads anywhere.
__global__ __launch_bounds__(128) void ta_wave_kernel(
    const float* __restrict__ X, const _Float16* __restrict__ Wt,
    const float* __restrict__ bq, const float* __restrict__ bk,
    const float* __restrict__ bv, const float* __restrict__ bf1,
    const float* __restrict__ bf2, float* __restrict__ Out)
{
    const int wid  = threadIdx.x >> 6;
    const int lane = threadIdx.x & 63;
    const int gw = blockIdx.x * 2 + wid;          // (b,n) index, 0..10399
    const int b = gw / NN, n = gw - b * NN;
    const int lr = lane & 15, lg = lane >> 4;

    __shared__ _Float16 qsh[2][TT * RSH];  // q, then attention-out
    __shared__ _Float16 ksh[2][TT * RSH];  // k, then FF1 hidden h
    __shared__ float    vsh[2][TT * RSF];  // v
    _Float16* q = qsh[wid];
    _Float16* k = ksh[wid];
    float*    v = vsh[wid];

    const size_t xbase = (((size_t)b * TT) * NN + n) * DD;

    // ---- A fragments of X: rows 16mt+lr, k = 16kt + 4lg + i ----
    h4 a[2][4];
    #pragma unroll
    for (int mt = 0; mt < 2; ++mt) {
        const int row = mt * 16 + lr;
        const bool ok = row < TT;
        const float* xp = X + xbase + (size_t)row * (NN * DD);
        #pragma unroll
        for (int kt = 0; kt < 4; ++kt) {
            f4 x = {0.f, 0.f, 0.f, 0.f};
            if (ok) x = *(const f4*)(xp + kt * 16 + lg * 4);
            h4 h;
            h[0] = (_Float16)x[0]; h[1] = (_Float16)x[1];
            h[2] = (_Float16)x[2]; h[3] = (_Float16)x[3];
            a[mt][kt] = h;
        }
    }

// Full-width matmul: this wave computes all 4 N-tiles. D layout: row=4lg+r, col=16nt+lr.
#define MATMUL_NT(WOFF, BIASP, STORE)                                            \
    {                                                                            \
        _Pragma("unroll")                                                        \
        for (int nt = 0; nt < 4; ++nt) {                                         \
            const int col = 16 * nt + lr;                                        \
            const _Float16* wp = Wt + (WOFF) + col * 64 + lg * 4;                \
            h4 bfr[4];                                                           \
            _Pragma("unroll")                                                    \
            for (int kt = 0; kt < 4; ++kt) bfr[kt] = *(const h4*)(wp + kt * 16); \
            const float bb = (BIASP)[col];                                       \
            f4 acc0 = {bb, bb, bb, bb};                                          \
            f4 acc1 = acc0;                                                      \
            _Pragma("unroll")                                                    \
            for (int kt = 0; kt < 4; ++kt) {                                     \
                acc0 = __builtin_amdgcn_mfma_f32_16x16x16f16(a[0][kt], bfr[kt], acc0, 0, 0, 0); \
                acc1 = __builtin_amdgcn_mfma_f32_16x16x16f16(a[1][kt], bfr[kt], acc1, 0, 0, 0); \
            }                                                                    \
            _Pragma("unroll")                                                    \
            for (int r = 0; r < 4; ++r) {                                        \
                const int row0 = 4 * lg + r;                                     \
                const int row1 = 16 + row0;                                      \
                STORE(row0, col, acc0[r]);                                       \
                if (row1 < TT) STORE(row1, col, acc1[r]);                        \
            }                                                                    \
        }                                                                        \
    }

#define STQ(rr, cc, vv) q[(rr) * RSH + (cc)] = (_Float16)fmaxf((vv), 0.f)
#define STK(rr, cc, vv) k[(rr) * RSH + (cc)] = (_Float16)fmaxf((vv), 0.f)
#define STV(rr, cc, vv) v[(rr) * RSF + (cc)] = fmaxf((vv), 0.f)
#define STH(rr, cc, vv) k[(rr) * RSH + (cc)] = (_Float16)fmaxf((vv), 0.f)
#define STO(rr, cc, vv) Out[xbase + (size_t)(rr) * (NN * DD) + (cc)] = (vv)

// Reload A fragments from an f16 LDS tile (attention-out or hidden h).
#define LOAD_AFRAG(SRC)                                                          \
    {                                                                            \
        _Pragma("unroll")                                                        \
        for (int mt = 0; mt < 2; ++mt) {                                         \
            const int row = 16 * mt + lr;                                        \
            _Pragma("unroll")                                                    \
            for (int kt = 0; kt < 4; ++kt) {                                     \
                h4 tmpf = {(_Float16)0, (_Float16)0, (_Float16)0, (_Float16)0};  \
                if (row < TT) tmpf = *(const h4*)&(SRC)[row * RSH + kt * 16 + lg * 4]; \
                a[mt][kt] = tmpf;                                                \
            }                                                                    \
        }                                                                        \
    }

    // ---- QKV ----
    MATMUL_NT(0 * 4096, bq, STQ)
    MATMUL_NT(1 * 4096, bk, STK)
    MATMUL_NT(2 * 4096, bv, STV)

    // ---- attention: 3 passes, lane = (kh = lane&7, tl = lane>>3), t = 8p + tl ----
    {
        const int kh = lane & 7;
        const int tl = lane >> 3;
        #pragma unroll
        for (int p = 0; p < 3; ++p) {
            const int t = 8 * p + tl;
            const h4 qa = *(const h4*)&q[t * RSH + kh * 8];
            const h4 qb = *(const h4*)&q[t * RSH + kh * 8 + 4];
            float sc[TT];
            float mx = -3.0e38f;
            #pragma unroll
            for (int s = 8 * p; s < TT; ++s) {
                const h4 ka = *(const h4*)&k[s * RSH + kh * 8];
                const h4 kb = *(const h4*)&k[s * RSH + kh * 8 + 4];
                float d = dot8(qa, qb, ka, kb) * 0.35355339059327373f;  // 1/sqrt(8)
                d = (s >= t) ? d : -3.0e38f;                            // upper triangle
                sc[s] = d;
                mx = fmaxf(mx, d);
            }
            float sum = 0.f;
            #pragma unroll
            for (int s = 8 * p; s < TT; ++s) {
                const float e = __expf(sc[s] - mx);                     // masked -> 0
                sc[s] = e;
                sum += e;
            }
            f4 oa = {0.f, 0.f, 0.f, 0.f}, ob = {0.f, 0.f, 0.f, 0.f};
            #pragma unroll
            for (int s = 8 * p; s < TT; ++s) {
                const f4 va = *(const f4*)&v[s * RSF + kh * 8];
                const f4 vb = *(const f4*)&v[s * RSF + kh * 8 + 4];
                const float pp = sc[s];
                oa += pp * va;
                ob += pp * vb;
            }
            const float inv = 1.f / sum;
            h4 ha, hb;
            #pragma unroll
            for (int i = 0; i < 4; ++i) {
                ha[i] = (_Float16)(oa[i] * inv);
                hb[i] = (_Float16)(ob[i] * inv);
            }
            // in-place over q: this lane is the only reader/writer of this segment
            *(h4*)&q[t * RSH + kh * 8]     = ha;
            *(h4*)&q[t * RSH + kh * 8 + 4] = hb;
        }
    }

    // ---- FF1: h = relu(out @ Wf1 + bf1), out in q -> h into k ----
    LOAD_AFRAG(q)
    MATMUL_NT(3 * 4096, bf1, STH)

    // ---- FF2: y = h @ Wf2 + bf2 -> global ----
    LOAD_AFRAG(k)
    MATMUL_NT(4 * 4096, bf2, STO)
}

extern "C" void kernel_launch(void* const* d_in, const int* in_sizes, int n_in,
                              void* d_out, int out_size, void* d_ws, size_t ws_size,
                              hipStream_t stream) {
    const float* X   = (const float*)d_in[0];
    // d_in[1] = STE (unused by the reference)
    const float* Wq  = (const float*)d_in[2];
    const float* bq  = (const float*)d_in[3];
    const float* Wk  = (const float*)d_in[4];
    const float* bk  = (const float*)d_in[5];
    const float* Wv  = (const float*)d_in[6];
    const float* bv  = (const float*)d_in[7];
    const float* Wf1 = (const float*)d_in[8];
    const float* bf1 = (const float*)d_in[9];
    const float* Wf2 = (const float*)d_in[10];
    const float* bf2 = (const float*)d_in[11];
    float* Out = (float*)d_out;

    _Float16* Wt = (_Float16*)d_ws;   // 5 * 64*64 f16 = 40 KB

    prep_w_kernel<<<5, 256, 0, stream>>>(Wq, Wk, Wv, Wf1, Wf2, Wt);
    ta_wave_kernel<<<(BB * NN) / 2, 128, 0, stream>>>(X, Wt, bq, bk, bv, bf1, bf2, Out);
}